// Round 19
// baseline (64.067 us; speedup 1.0000x reference)
//
#include <hip/hip_runtime.h>

#define N 512
#define ADJW (N/64)
#define MAXC 64
typedef unsigned long long ull;

__device__ __forceinline__ float limit_period_f(float v){
    const float TWO_PI_F = 6.2831853071795864769f;
    return v - floorf(v/TWO_PI_F + 0.5f)*TWO_PI_F;
}
__device__ __forceinline__ unsigned fkey(float f){
    unsigned u = __float_as_uint(f);
    return (u & 0x80000000u) ? ~u : (u | 0x80000000u);
}
__device__ __forceinline__ float fdec(unsigned k){
    unsigned u = (k & 0x80000000u) ? (k ^ 0x80000000u) : ~k;
    return __uint_as_float(u);
}

// ==== adj_kernel: byte-identical to rounds 10-18 (proven, exact bits) ====
__global__ __launch_bounds__(512) void adj_kernel(const float* __restrict__ boxes,
                                                  ull* __restrict__ adj){
    int i = blockIdx.x;
    int t = threadIdx.x;
    int l = t & 63, wv = t >> 6;
    int h  = l >> 5;
    int sl = l & 31;
    int hb = wv*2 + h;

    __shared__ int      s_wcnt[8];
    __shared__ int      s_list[MAXC];
    __shared__ unsigned s_row[ADJW*2];
    __shared__ float    s_boxes[N][7];
    __shared__ float    s_px[16][24], s_py[16][24], s_ang[16][24];
    __shared__ float    s_rx[16][24], s_ry[16][24], s_tm[16][24];

    if(t < ADJW*2) s_row[t] = 0u;

    float bi0=boxes[i*7+0], bi1=boxes[i*7+1], bi2=boxes[i*7+2], bi3=boxes[i*7+3],
          bi4=boxes[i*7+4], bi5=boxes[i*7+5], bi6=boxes[i*7+6];
    int j = t;
    float bj0=boxes[j*7+0], bj1=boxes[j*7+1], bj2=boxes[j*7+2], bj3=boxes[j*7+3],
          bj4=boxes[j*7+4], bj5=boxes[j*7+5], bj6=boxes[j*7+6];
    s_boxes[t][0]=bj0; s_boxes[t][1]=bj1; s_boxes[t][2]=bj2; s_boxes[t][3]=bj3;
    s_boxes[t][4]=bj4; s_boxes[t][5]=bj5; s_boxes[t][6]=bj6;

    float topi = bi2 + bi3*0.5f, boti = bi2 - bi3*0.5f;
    float topj = bj2 + bj3*0.5f, botj = bj2 - bj3*0.5f;
    float ohc = fminf(topi, topj) - fmaxf(boti, botj);
    float dx = bi0 - bj0, dy = bi1 - bj1;
    float ra = 0.5f*sqrtf(bi5*bi5 + bi4*bi4);
    float rb = 0.5f*sqrtf(bj5*bj5 + bj4*bj4);
    float rr = ra + rb + 0.01f;
    bool cand = (dx*dx + dy*dy <= rr*rr) && (ohc > 0.0f);

    ull m = __ballot(cand);
    if(l == 0) s_wcnt[wv] = __popcll(m);
    int prefix = __popcll(m & ((1ull<<l) - 1ull));
    __syncthreads();
    int base = 0, C = 0;
    #pragma unroll
    for(int k=0;k<8;++k){ int c = s_wcnt[k]; if(k < wv) base += c; C += c; }
    if(cand){
        int pos = base + prefix;
        if(pos < MAXC) s_list[pos] = j;
    }
    if(C > MAXC) C = MAXC;
    __syncthreads();

    float voli = bi3*bi4*bi5;
    const float tx[4] = {0.5f, 0.5f, -0.5f, -0.5f};
    const float ty[4] = {0.5f, -0.5f, -0.5f, 0.5f};
    float yawi = limit_period_f(bi6);
    float cA = cosf(yawi), sA = sinf(yawi);
    float axv[4], ayv[4];
    #pragma unroll
    for(int k=0;k<4;++k){
        float px = tx[k]*bi5, py = ty[k]*bi4;
        axv[k] = px*cA - py*sA + bi0;
        ayv[k] = px*sA + py*cA + bi1;
    }

    for(int k = hb; k < C; k += 16){
        int jj = s_list[k];
        float cj0=s_boxes[jj][0], cj1=s_boxes[jj][1], cj2=s_boxes[jj][2],
              cj3=s_boxes[jj][3], cj4=s_boxes[jj][4], cj5=s_boxes[jj][5],
              cj6=s_boxes[jj][6];
        float volj = cj3*cj4*cj5;
        float topj2 = cj2 + cj3*0.5f, botj2 = cj2 - cj3*0.5f;
        float oh = fminf(topi, topj2) - fmaxf(boti, botj2);
        float yawj = limit_period_f(cj6);
        float cB = cosf(yawj), sB = sinf(yawj);
        float bxv[4], byv[4];
        #pragma unroll
        for(int kk=0;kk<4;++kk){
            float qx = tx[kk]*cj5, qy = ty[kk]*cj4;
            bxv[kk] = qx*cB - qy*sB + cj0;
            byv[kk] = qx*sB + qy*cB + cj1;
        }

        const float EPSQ = 1e-5f;
        bool valid = false;
        float px = 0.f, py = 0.f;
        if(sl < 16){
            int e1 = sl >> 2, e2 = sl & 3;
            float a1x=axv[e1], a1y=ayv[e1];
            float d1x=axv[(e1+1)&3]-a1x, d1y=ayv[(e1+1)&3]-a1y;
            float b1x=bxv[e2], b1y=byv[e2];
            float d2x=bxv[(e2+1)&3]-b1x, d2y=byv[(e2+1)&3]-b1y;
            float den = d1x*d2y - d1y*d2x;
            bool okd = fabsf(den) > 1e-8f;
            float dens = okd ? den : 1e-8f;
            float wx = b1x-a1x, wy = b1y-a1y;
            float tt = (wx*d2y - wy*d2x)/dens;
            float uu = (wx*d1y - wy*d1x)/dens;
            valid = okd && (tt>=0.f) && (tt<=1.f) && (uu>=0.f) && (uu<=1.f);
            px = a1x + tt*d1x;
            py = a1y + tt*d1y;
        } else if(sl < 20){
            int kk = sl - 16;
            px = axv[kk]; py = ayv[kk];
            bool le=true, ge=true;
            #pragma unroll
            for(int e=0;e<4;++e){
                float qx=bxv[e], qy=byv[e];
                float ux=bxv[(e+1)&3]-qx, uy=byv[(e+1)&3]-qy;
                float cc = ux*(py-qy) - uy*(px-qx);
                le = le && (cc <= EPSQ);
                ge = ge && (cc >= -EPSQ);
            }
            valid = le || ge;
        } else if(sl < 24){
            int kk = sl - 20;
            px = bxv[kk]; py = byv[kk];
            bool le=true, ge=true;
            #pragma unroll
            for(int e=0;e<4;++e){
                float qx=axv[e], qy=ayv[e];
                float ux=axv[(e+1)&3]-qx, uy=ayv[(e+1)&3]-qy;
                float cc = ux*(py-qy) - uy*(px-qx);
                le = le && (cc <= EPSQ);
                ge = ge && (cc >= -EPSQ);
            }
            valid = le || ge;
        }

        ull bm = __ballot(valid);
        unsigned mh = (unsigned)(bm >> (h*32)) & 0xFFFFFFu;
        int c = __popc(mh);
        float cntf = (float)c;

        if(sl < 24){
            s_px[hb][sl] = valid ? px : 0.f;
            s_py[hb][sl] = valid ? py : 0.f;
        }
        asm volatile("s_waitcnt lgkmcnt(0)" ::: "memory");
        float sx = 0.f, sy = 0.f;
        if(sl == 0){
            #pragma unroll
            for(int kk=0;kk<24;++kk){ sx += s_px[hb][kk]; sy += s_py[hb][kk]; }
        }
        sx = __shfl(sx, l & 32);
        sy = __shfl(sy, l & 32);
        float denomc = fmaxf(cntf, 1.f);
        float cenx = sx/denomc, ceny = sy/denomc;

        float relx = valid ? (px - cenx) : 0.f;
        float rely = valid ? (py - ceny) : 0.f;
        float ang  = valid ? atan2f(rely, relx) : 1e9f;

        if(sl < 24) s_ang[hb][sl] = ang;
        asm volatile("s_waitcnt lgkmcnt(0)" ::: "memory");
        int r = 0;
        if(sl < 24){
            #pragma unroll
            for(int qq=0; qq<24; ++qq){
                float aq = s_ang[hb][qq];
                if(aq < ang) r++;
                else if(aq == ang && qq < sl) r++;
            }
        }

        if(sl < 24){
            s_rx[hb][r] = relx;
            s_ry[hb][r] = rely;
        }
        asm volatile("s_waitcnt lgkmcnt(0)" ::: "memory");
        if(sl < 24){
            int nxt = (r+1 < c) ? (r+1) : 0;
            float nx = s_rx[hb][nxt], ny = s_ry[hb][nxt];
            float tm = (r < c) ? (relx*ny - rely*nx) : 0.f;
            s_tm[hb][r] = tm;
        }
        asm volatile("s_waitcnt lgkmcnt(0)" ::: "memory");

        if(sl == 0){
            float acc = 0.f;
            #pragma unroll
            for(int kk=0;kk<24;++kk) acc += s_tm[hb][kk];
            float area = 0.5f*fabsf(acc);
            float inter_bev = (cntf >= 3.f) ? area : 0.f;
            float inter = inter_bev * oh;
            float iou = inter / fmaxf(voli+volj-inter, 1e-6f);
            if(iou > 0.1f) atomicOr(&s_row[jj>>5], 1u << (jj&31));
        }
    }
    __syncthreads();
    if(t < ADJW) adj[i*ADJW + t] = ((ull*)s_row)[t];
}

// ==== cluster_fuse: pass-1 clustering with DEPTH-2 SCALAR prefetch of the
//      critical word (word g of next candidate seeds); deferred parallel
//      assignment (r18); atomic fuse phases (byte-identical to r16/r18). ====
__global__ __launch_bounds__(512) void cluster_fuse_kernel(
        const float* __restrict__ boxes,
        const float* __restrict__ scores,
        const ull* __restrict__ adj,
        const int* __restrict__ fhp,
        const int* __restrict__ fwp,
        float* __restrict__ out){
    const float PI_F      = 3.14159265358979323846f;
    const float HALF_PI_F = 1.57079632679489662f;
    const float TWO_PI_F  = 6.2831853071795864769f;
    int t = threadIdx.x;

    __shared__ ull      s_adj[N*ADJW];    // 32 KB
    __shared__ int      s_seed[N];        // seed index list (cid = k+1)
    __shared__ int      s_nseed;
    __shared__ int      s_cnt[N];
    __shared__ unsigned s_smaxk[N];
    __shared__ unsigned s_drefk[N];
    __shared__ float    s_ssum[N];
    __shared__ float    s_slt[N], s_sle[N];
    __shared__ float    s_acc[8][N];

    float b0=boxes[t*7+0], b1=boxes[t*7+1], b2=boxes[t*7+2], b3=boxes[t*7+3],
          b4=boxes[t*7+4], b5=boxes[t*7+5], b6=boxes[t*7+6];
    float dir = limit_period_f(b6);
    float sc  = scores[t];
    s_cnt[t] = 0;
    s_smaxk[t] = fkey(-1e30f);
    s_drefk[t] = fkey(-1e9f);
    s_ssum[t] = 0.f;
    s_slt[t] = 0.f;
    s_sle[t] = 0.f;
    #pragma unroll
    for(int k=0;k<8;++k) s_acc[k][t] = 0.f;
    #pragma unroll
    for(int k=0;k<ADJW;++k) s_adj[k*N + t] = adj[k*N + t];
    __syncthreads();

    // ---- clustering pass 1: wave 0, replicated coverage; seeds only.
    //      Critical chain: OR(reg) -> ffs -> select; word g of the next two
    //      candidate seeds is prefetched into SCALAR regs (w1,w2) >=1-2
    //      iterations ahead. Other 7 coverage words OR'd off-chain.
    //      Seed order provably identical to the reference greedy. ----
    if(t < 64){
        ull cov[8] = {0,0,0,0,0,0,0,0};
        int cnt = 0;
        #pragma unroll
        for(int g=0; g<8; ++g){
            ull cg = cov[g];
            ull rem0 = ~cg;
            if(rem0 == 0ull) continue;
            int cur = (int)__ffsll(rem0) - 1;
            ull wcur = s_adj[(g*64+cur)*8 + g];
            ull pool0 = rem0 ^ (1ull << cur);
            int c1 = -1, c2 = -1; ull w1 = 0, w2 = 0;
            if(pool0){
                c1 = (int)__ffsll(pool0) - 1; pool0 ^= (1ull << c1);
                w1 = s_adj[(g*64+c1)*8 + g];
            }
            if(pool0){
                c2 = (int)__ffsll(pool0) - 1;
                w2 = s_adj[(g*64+c2)*8 + g];
            }
            for(;;){
                int seed = g*64 + cur;
                if(t == 0) s_seed[cnt] = seed;
                cnt++;
                // off-chain: other coverage words
                #pragma unroll
                for(int k=0;k<8;++k){ if(k != g) cov[k] |= s_adj[seed*8 + k]; }
                cg |= wcur;
                ull rem = ~cg;
                if(rem == 0ull) break;
                int nb = (int)__ffsll(rem) - 1;
                // resolve wcur (hit: register move; miss: direct load)
                if(nb == c1){ wcur = w1; c1 = -1; }
                else if(nb == c2){ wcur = w2; c2 = -1; }
                else { wcur = s_adj[(g*64+nb)*8 + g]; }
                cur = nb;
                // drop stale candidates (<= nb or now covered)
                if(c1 >= 0 && (c1 <= nb || !((rem >> c1) & 1ull))) c1 = -1;
                if(c2 >= 0 && (c2 <= nb || !((rem >> c2) & 1ull))) c2 = -1;
                if(c1 < 0){ c1 = c2; w1 = w2; c2 = -1; }
                // refill from unset bits strictly greater than nb, != c1
                ull hide = (nb < 63) ? ((1ull << (nb+1)) - 1ull) : ~0ull;
                ull p = rem & ~hide;
                if(c1 >= 0) p &= ~(1ull << c1);
                if(c1 < 0 && p){
                    c1 = (int)__ffsll(p) - 1; p ^= (1ull << c1);
                    w1 = s_adj[(g*64+c1)*8 + g];
                }
                if(c2 < 0 && p){
                    c2 = (int)__ffsll(p) - 1;
                    w2 = s_adj[(g*64+c2)*8 + g];
                }
            }
            cov[g] = cg;
        }
        if(t == 0) s_nseed = cnt;
    }
    __syncthreads();

    // ---- clustering pass 2: all 512 threads self-assign in parallel.
    //      ci(t) = (index of LAST seed whose row covers t) + 1. ----
    int myci = 0;
    {
        const unsigned char* ab = (const unsigned char*)s_adj;
        int byteoff = t >> 3;
        unsigned bit = (unsigned)(t & 7);
        int nb = s_nseed;
        for(int k=0; k<nb; ++k){
            int s = s_seed[k];
            unsigned byte = (unsigned)ab[s*64 + byteoff];
            if((byte >> bit) & 1u) myci = k + 1;
        }
    }
    int ow = myci - 1;

    // phase A: count, exact smax, score sum
    atomicAdd(&s_cnt[ow], 1);
    atomicMax(&s_smaxk[ow], fkey(sc));
    atomicAdd(&s_ssum[ow], sc);
    __syncthreads();

    // phase B: exact dref = max{dir : sc == smax}
    float smax_b = fdec(s_smaxk[ow]);
    if(sc == smax_b) atomicMax(&s_drefk[ow], fkey(dir));
    __syncthreads();

    // phase C: gt decision, slt/sle masses
    float drefb = fdec(s_drefk[ow]);
    float diff = fabsf(dir - drefb);
    diff = (diff > PI_F) ? (TWO_PI_F - diff) : diff;
    bool gt = diff > HALF_PI_F;
    atomicAdd(gt ? &s_slt[ow] : &s_sle[ow], sc);
    __syncthreads();

    // phase D: flip, trig, weighted contributions
    {
        bool keep = (s_slt[ow] <= s_sle[ow]);
        bool flip = keep ? gt : !gt;
        float d2 = limit_period_f(dir + (flip ? PI_F : 0.f));
        float sn = sc / s_ssum[ow];
        atomicAdd(&s_acc[0][ow], sinf(d2)*sn);
        atomicAdd(&s_acc[1][ow], cosf(d2)*sn);
        atomicAdd(&s_acc[2][ow], b0*sn);
        atomicAdd(&s_acc[3][ow], b1*sn);
        atomicAdd(&s_acc[4][ow], b2*sn);
        atomicAdd(&s_acc[5][ow], b3*sn);
        atomicAdd(&s_acc[6][ow], b4*sn);
        atomicAdd(&s_acc[7][ow], b5*sn);
    }
    __syncthreads();

    // owner epilogue: thread t owns segment t+1
    int icnt = s_cnt[t];
    float smax = fdec(s_smaxk[t]);
    float theta = atan2f(s_acc[0][t], s_acc[1][t]);
    bool valid = icnt > 0;
    float bf[7];
    bf[0] = valid ? s_acc[2][t] : 0.f;
    bf[1] = valid ? s_acc[3][t] : 0.f;
    bf[2] = valid ? s_acc[4][t] : 0.f;
    bf[3] = valid ? s_acc[5][t] : 0.f;
    bf[4] = valid ? s_acc[6][t] : 0.f;
    bf[5] = valid ? s_acc[7][t] : 0.f;
    bf[6] = valid ? theta : 0.f;
    {
        float cth=cosf(bf[6]), sth=sinf(bf[6]);
        const float tx[4]={0.5f,0.5f,-0.5f,-0.5f};
        const float ty[4]={0.5f,-0.5f,-0.5f,0.5f};
        bool inb = true;
        #pragma unroll
        for(int k=0;k<4;++k){
            float pxl = tx[k]*bf[5], pyl = ty[k]*bf[4];
            float gx = pxl*cth - pyl*sth + bf[0];
            float gy = pxl*sth + pyl*cth + bf[1];
            inb = inb && (gx > -140.8f) && (gx < 140.8f) && (gy > -40.0f) && (gy < 40.0f);
        }
        valid = valid && inb;
    }
    if(!valid){
        #pragma unroll
        for(int d=0;d<7;++d) bf[d]=0.f;
    }
    float sf = valid ? smax : 0.f;
    int fh = *fhp, fw = *fwp;
    float ghf = (float)((40.0 - (-40.0)) / (double)fh);
    float gwf = (float)((140.8 - (-140.8)) / (double)fw);
    float gcx = (bf[0] + 140.8f) / gwf;
    float gcy = (bf[1] + 40.0f) / ghf;
    float gox = bf[5]*0.5f / gwf;
    float goy = bf[4]*0.5f / ghf + 1.0f;
    float xmin = fmaxf(gcx - gox, 0.f);
    float xmax = fminf(gcx + gox, (float)fw - 1.0f);
    float ymin = fmaxf(gcy - goy, 0.f);
    float ymax = fminf(gcy + goy, (float)fh - 1.0f);
    int r0 = (int)xmin, r1 = (int)xmax, r2 = (int)ymin, r3 = (int)ymax;
    if(!valid){ r0=0; r1=0; r2=0; r3=0; }
    #pragma unroll
    for(int d=0;d<7;++d) out[t*7+d] = bf[d];
    out[N*7 + t] = sf;
    out[N*8 + t] = valid ? 1.f : 0.f;
    out[N*9 + t*4 + 0] = (float)r0;
    out[N*9 + t*4 + 1] = (float)r1;
    out[N*9 + t*4 + 2] = (float)r2;
    out[N*9 + t*4 + 3] = (float)r3;
}

extern "C" void kernel_launch(void* const* d_in, const int* in_sizes, int n_in,
                              void* d_out, int out_size, void* d_ws, size_t ws_size,
                              hipStream_t stream) {
    const float* boxes  = (const float*)d_in[0];
    const float* scores = (const float*)d_in[1];
    const int*   fhp    = (const int*)d_in[2];
    const int*   fwp    = (const int*)d_in[3];
    float* out = (float*)d_out;
    ull* adj = (ull*)d_ws;               // 32768 bytes

    adj_kernel<<<N, 512, 0, stream>>>(boxes, adj);
    cluster_fuse_kernel<<<1, 512, 0, stream>>>(boxes, scores, adj, fhp, fwp, out);
}

// Round 20
// 38.430 us; speedup vs baseline: 1.6671x; 1.6671x over previous
//
#include <hip/hip_runtime.h>

#define N 512
#define ADJW (N/64)
#define MAXC 64
typedef unsigned long long ull;

__device__ __forceinline__ float limit_period_f(float v){
    const float TWO_PI_F = 6.2831853071795864769f;
    return v - floorf(v/TWO_PI_F + 0.5f)*TWO_PI_F;
}
__device__ __forceinline__ unsigned fkey(float f){
    unsigned u = __float_as_uint(f);
    return (u & 0x80000000u) ? ~u : (u | 0x80000000u);
}
__device__ __forceinline__ float fdec(unsigned k){
    unsigned u = (k & 0x80000000u) ? (k ^ 0x80000000u) : ~k;
    return __uint_as_float(u);
}

// ==== adj_kernel: byte-identical to rounds 10-18 (proven, exact bits) ====
__global__ __launch_bounds__(512) void adj_kernel(const float* __restrict__ boxes,
                                                  ull* __restrict__ adj){
    int i = blockIdx.x;
    int t = threadIdx.x;
    int l = t & 63, wv = t >> 6;
    int h  = l >> 5;
    int sl = l & 31;
    int hb = wv*2 + h;

    __shared__ int      s_wcnt[8];
    __shared__ int      s_list[MAXC];
    __shared__ unsigned s_row[ADJW*2];
    __shared__ float    s_boxes[N][7];
    __shared__ float    s_px[16][24], s_py[16][24], s_ang[16][24];
    __shared__ float    s_rx[16][24], s_ry[16][24], s_tm[16][24];

    if(t < ADJW*2) s_row[t] = 0u;

    float bi0=boxes[i*7+0], bi1=boxes[i*7+1], bi2=boxes[i*7+2], bi3=boxes[i*7+3],
          bi4=boxes[i*7+4], bi5=boxes[i*7+5], bi6=boxes[i*7+6];
    int j = t;
    float bj0=boxes[j*7+0], bj1=boxes[j*7+1], bj2=boxes[j*7+2], bj3=boxes[j*7+3],
          bj4=boxes[j*7+4], bj5=boxes[j*7+5], bj6=boxes[j*7+6];
    s_boxes[t][0]=bj0; s_boxes[t][1]=bj1; s_boxes[t][2]=bj2; s_boxes[t][3]=bj3;
    s_boxes[t][4]=bj4; s_boxes[t][5]=bj5; s_boxes[t][6]=bj6;

    float topi = bi2 + bi3*0.5f, boti = bi2 - bi3*0.5f;
    float topj = bj2 + bj3*0.5f, botj = bj2 - bj3*0.5f;
    float ohc = fminf(topi, topj) - fmaxf(boti, botj);
    float dx = bi0 - bj0, dy = bi1 - bj1;
    float ra = 0.5f*sqrtf(bi5*bi5 + bi4*bi4);
    float rb = 0.5f*sqrtf(bj5*bj5 + bj4*bj4);
    float rr = ra + rb + 0.01f;
    bool cand = (dx*dx + dy*dy <= rr*rr) && (ohc > 0.0f);

    ull m = __ballot(cand);
    if(l == 0) s_wcnt[wv] = __popcll(m);
    int prefix = __popcll(m & ((1ull<<l) - 1ull));
    __syncthreads();
    int base = 0, C = 0;
    #pragma unroll
    for(int k=0;k<8;++k){ int c = s_wcnt[k]; if(k < wv) base += c; C += c; }
    if(cand){
        int pos = base + prefix;
        if(pos < MAXC) s_list[pos] = j;
    }
    if(C > MAXC) C = MAXC;
    __syncthreads();

    float voli = bi3*bi4*bi5;
    const float tx[4] = {0.5f, 0.5f, -0.5f, -0.5f};
    const float ty[4] = {0.5f, -0.5f, -0.5f, 0.5f};
    float yawi = limit_period_f(bi6);
    float cA = cosf(yawi), sA = sinf(yawi);
    float axv[4], ayv[4];
    #pragma unroll
    for(int k=0;k<4;++k){
        float px = tx[k]*bi5, py = ty[k]*bi4;
        axv[k] = px*cA - py*sA + bi0;
        ayv[k] = px*sA + py*cA + bi1;
    }

    for(int k = hb; k < C; k += 16){
        int jj = s_list[k];
        float cj0=s_boxes[jj][0], cj1=s_boxes[jj][1], cj2=s_boxes[jj][2],
              cj3=s_boxes[jj][3], cj4=s_boxes[jj][4], cj5=s_boxes[jj][5],
              cj6=s_boxes[jj][6];
        float volj = cj3*cj4*cj5;
        float topj2 = cj2 + cj3*0.5f, botj2 = cj2 - cj3*0.5f;
        float oh = fminf(topi, topj2) - fmaxf(boti, botj2);
        float yawj = limit_period_f(cj6);
        float cB = cosf(yawj), sB = sinf(yawj);
        float bxv[4], byv[4];
        #pragma unroll
        for(int kk=0;kk<4;++kk){
            float qx = tx[kk]*cj5, qy = ty[kk]*cj4;
            bxv[kk] = qx*cB - qy*sB + cj0;
            byv[kk] = qx*sB + qy*cB + cj1;
        }

        const float EPSQ = 1e-5f;
        bool valid = false;
        float px = 0.f, py = 0.f;
        if(sl < 16){
            int e1 = sl >> 2, e2 = sl & 3;
            float a1x=axv[e1], a1y=ayv[e1];
            float d1x=axv[(e1+1)&3]-a1x, d1y=ayv[(e1+1)&3]-a1y;
            float b1x=bxv[e2], b1y=byv[e2];
            float d2x=bxv[(e2+1)&3]-b1x, d2y=byv[(e2+1)&3]-b1y;
            float den = d1x*d2y - d1y*d2x;
            bool okd = fabsf(den) > 1e-8f;
            float dens = okd ? den : 1e-8f;
            float wx = b1x-a1x, wy = b1y-a1y;
            float tt = (wx*d2y - wy*d2x)/dens;
            float uu = (wx*d1y - wy*d1x)/dens;
            valid = okd && (tt>=0.f) && (tt<=1.f) && (uu>=0.f) && (uu<=1.f);
            px = a1x + tt*d1x;
            py = a1y + tt*d1y;
        } else if(sl < 20){
            int kk = sl - 16;
            px = axv[kk]; py = ayv[kk];
            bool le=true, ge=true;
            #pragma unroll
            for(int e=0;e<4;++e){
                float qx=bxv[e], qy=byv[e];
                float ux=bxv[(e+1)&3]-qx, uy=byv[(e+1)&3]-qy;
                float cc = ux*(py-qy) - uy*(px-qx);
                le = le && (cc <= EPSQ);
                ge = ge && (cc >= -EPSQ);
            }
            valid = le || ge;
        } else if(sl < 24){
            int kk = sl - 20;
            px = bxv[kk]; py = byv[kk];
            bool le=true, ge=true;
            #pragma unroll
            for(int e=0;e<4;++e){
                float qx=axv[e], qy=ayv[e];
                float ux=axv[(e+1)&3]-qx, uy=ayv[(e+1)&3]-qy;
                float cc = ux*(py-qy) - uy*(px-qx);
                le = le && (cc <= EPSQ);
                ge = ge && (cc >= -EPSQ);
            }
            valid = le || ge;
        }

        ull bm = __ballot(valid);
        unsigned mh = (unsigned)(bm >> (h*32)) & 0xFFFFFFu;
        int c = __popc(mh);
        float cntf = (float)c;

        if(sl < 24){
            s_px[hb][sl] = valid ? px : 0.f;
            s_py[hb][sl] = valid ? py : 0.f;
        }
        asm volatile("s_waitcnt lgkmcnt(0)" ::: "memory");
        float sx = 0.f, sy = 0.f;
        if(sl == 0){
            #pragma unroll
            for(int kk=0;kk<24;++kk){ sx += s_px[hb][kk]; sy += s_py[hb][kk]; }
        }
        sx = __shfl(sx, l & 32);
        sy = __shfl(sy, l & 32);
        float denomc = fmaxf(cntf, 1.f);
        float cenx = sx/denomc, ceny = sy/denomc;

        float relx = valid ? (px - cenx) : 0.f;
        float rely = valid ? (py - ceny) : 0.f;
        float ang  = valid ? atan2f(rely, relx) : 1e9f;

        if(sl < 24) s_ang[hb][sl] = ang;
        asm volatile("s_waitcnt lgkmcnt(0)" ::: "memory");
        int r = 0;
        if(sl < 24){
            #pragma unroll
            for(int qq=0; qq<24; ++qq){
                float aq = s_ang[hb][qq];
                if(aq < ang) r++;
                else if(aq == ang && qq < sl) r++;
            }
        }

        if(sl < 24){
            s_rx[hb][r] = relx;
            s_ry[hb][r] = rely;
        }
        asm volatile("s_waitcnt lgkmcnt(0)" ::: "memory");
        if(sl < 24){
            int nxt = (r+1 < c) ? (r+1) : 0;
            float nx = s_rx[hb][nxt], ny = s_ry[hb][nxt];
            float tm = (r < c) ? (relx*ny - rely*nx) : 0.f;
            s_tm[hb][r] = tm;
        }
        asm volatile("s_waitcnt lgkmcnt(0)" ::: "memory");

        if(sl == 0){
            float acc = 0.f;
            #pragma unroll
            for(int kk=0;kk<24;++kk) acc += s_tm[hb][kk];
            float area = 0.5f*fabsf(acc);
            float inter_bev = (cntf >= 3.f) ? area : 0.f;
            float inter = inter_bev * oh;
            float iou = inter / fmaxf(voli+volj-inter, 1e-6f);
            if(iou > 0.1f) atomicOr(&s_row[jj>>5], 1u << (jj&31));
        }
    }
    __syncthreads();
    if(t < ADJW) adj[i*ADJW + t] = ((ull*)s_row)[t];
}

// ==== cluster_fuse: r16 verbatim — replicated-coverage clustering (wave 0)
//      + atomic fuse phases. Best-known build (38.4 us, absmax 0.0). ====
__global__ __launch_bounds__(512) void cluster_fuse_kernel(
        const float* __restrict__ boxes,
        const float* __restrict__ scores,
        const ull* __restrict__ adj,
        const int* __restrict__ fhp,
        const int* __restrict__ fwp,
        float* __restrict__ out){
    const float PI_F      = 3.14159265358979323846f;
    const float HALF_PI_F = 1.57079632679489662f;
    const float TWO_PI_F  = 6.2831853071795864769f;
    int t = threadIdx.x;

    __shared__ ull      s_adj[N*ADJW];    // 32 KB
    __shared__ int      s_ci[N];
    __shared__ int      s_cnt[N];
    __shared__ unsigned s_smaxk[N];
    __shared__ unsigned s_drefk[N];
    __shared__ float    s_ssum[N];
    __shared__ float    s_slt[N], s_sle[N];
    __shared__ float    s_acc[8][N];

    float b0=boxes[t*7+0], b1=boxes[t*7+1], b2=boxes[t*7+2], b3=boxes[t*7+3],
          b4=boxes[t*7+4], b5=boxes[t*7+5], b6=boxes[t*7+6];
    float dir = limit_period_f(b6);
    float sc  = scores[t];
    s_cnt[t] = 0;
    s_smaxk[t] = fkey(-1e30f);
    s_drefk[t] = fkey(-1e9f);
    s_ssum[t] = 0.f;
    s_slt[t] = 0.f;
    s_sle[t] = 0.f;
    #pragma unroll
    for(int k=0;k<8;++k) s_acc[k][t] = 0.f;
    #pragma unroll
    for(int k=0;k<ADJW;++k) s_adj[k*N + t] = adj[k*N + t];
    __syncthreads();

    // ---- clustering: wave 0, replicated 512-bit coverage in VGPRs.
    //      Critical chain per seed: ffs -> LDS b64 broadcast read -> OR.
    //      (Software speculation attempts regressed twice — r17/r19 — the
    //      compiler-scheduled simple loop is the measured optimum.) ----
    if(t < 64){
        const unsigned char* ab = (const unsigned char*)s_adj;
        ull cov[8] = {0,0,0,0,0,0,0,0};
        int mc[8]  = {0,0,0,0,0,0,0,0};
        int cid = 1;
        #pragma unroll
        for(int g=0; g<8; ++g){
            ull cg2 = cov[g];
            while(~cg2 != 0ull){
                int b = (int)__ffsll(~cg2) - 1;
                int seed = g*64 + b;
                cov[g] |= s_adj[seed*8 + g];          // critical-chain word first
                unsigned myb = (unsigned)ab[seed*64 + t];
                #pragma unroll
                for(int k=0;k<8;++k){ if(k != g) cov[k] |= s_adj[seed*8 + k]; }
                #pragma unroll
                for(int q=0;q<8;++q){ if((myb>>q)&1u) mc[q] = cid; }
                cid++;
                cg2 = cov[g];                          // diagonal bit guarantees progress
            }
        }
        #pragma unroll
        for(int q=0;q<8;++q) s_ci[t*8+q] = mc[q];
    }
    __syncthreads();

    int ow = s_ci[t] - 1;

    // phase A: count, exact smax, score sum
    atomicAdd(&s_cnt[ow], 1);
    atomicMax(&s_smaxk[ow], fkey(sc));
    atomicAdd(&s_ssum[ow], sc);
    __syncthreads();

    // phase B: exact dref = max{dir : sc == smax}
    float smax_b = fdec(s_smaxk[ow]);
    if(sc == smax_b) atomicMax(&s_drefk[ow], fkey(dir));
    __syncthreads();

    // phase C: gt decision, slt/sle masses
    float drefb = fdec(s_drefk[ow]);
    float diff = fabsf(dir - drefb);
    diff = (diff > PI_F) ? (TWO_PI_F - diff) : diff;
    bool gt = diff > HALF_PI_F;
    atomicAdd(gt ? &s_slt[ow] : &s_sle[ow], sc);
    __syncthreads();

    // phase D: flip, trig, weighted contributions
    {
        bool keep = (s_slt[ow] <= s_sle[ow]);
        bool flip = keep ? gt : !gt;
        float d2 = limit_period_f(dir + (flip ? PI_F : 0.f));
        float sn = sc / s_ssum[ow];
        atomicAdd(&s_acc[0][ow], sinf(d2)*sn);
        atomicAdd(&s_acc[1][ow], cosf(d2)*sn);
        atomicAdd(&s_acc[2][ow], b0*sn);
        atomicAdd(&s_acc[3][ow], b1*sn);
        atomicAdd(&s_acc[4][ow], b2*sn);
        atomicAdd(&s_acc[5][ow], b3*sn);
        atomicAdd(&s_acc[6][ow], b4*sn);
        atomicAdd(&s_acc[7][ow], b5*sn);
    }
    __syncthreads();

    // owner epilogue: thread t owns segment t+1
    int icnt = s_cnt[t];
    float smax = fdec(s_smaxk[t]);
    float theta = atan2f(s_acc[0][t], s_acc[1][t]);
    bool valid = icnt > 0;
    float bf[7];
    bf[0] = valid ? s_acc[2][t] : 0.f;
    bf[1] = valid ? s_acc[3][t] : 0.f;
    bf[2] = valid ? s_acc[4][t] : 0.f;
    bf[3] = valid ? s_acc[5][t] : 0.f;
    bf[4] = valid ? s_acc[6][t] : 0.f;
    bf[5] = valid ? s_acc[7][t] : 0.f;
    bf[6] = valid ? theta : 0.f;
    {
        float cth=cosf(bf[6]), sth=sinf(bf[6]);
        const float tx[4]={0.5f,0.5f,-0.5f,-0.5f};
        const float ty[4]={0.5f,-0.5f,-0.5f,0.5f};
        bool inb = true;
        #pragma unroll
        for(int k=0;k<4;++k){
            float pxl = tx[k]*bf[5], pyl = ty[k]*bf[4];
            float gx = pxl*cth - pyl*sth + bf[0];
            float gy = pxl*sth + pyl*cth + bf[1];
            inb = inb && (gx > -140.8f) && (gx < 140.8f) && (gy > -40.0f) && (gy < 40.0f);
        }
        valid = valid && inb;
    }
    if(!valid){
        #pragma unroll
        for(int d=0;d<7;++d) bf[d]=0.f;
    }
    float sf = valid ? smax : 0.f;
    int fh = *fhp, fw = *fwp;
    float ghf = (float)((40.0 - (-40.0)) / (double)fh);
    float gwf = (float)((140.8 - (-140.8)) / (double)fw);
    float gcx = (bf[0] + 140.8f) / gwf;
    float gcy = (bf[1] + 40.0f) / ghf;
    float gox = bf[5]*0.5f / gwf;
    float goy = bf[4]*0.5f / ghf + 1.0f;
    float xmin = fmaxf(gcx - gox, 0.f);
    float xmax = fminf(gcx + gox, (float)fw - 1.0f);
    float ymin = fmaxf(gcy - goy, 0.f);
    float ymax = fminf(gcy + goy, (float)fh - 1.0f);
    int r0 = (int)xmin, r1 = (int)xmax, r2 = (int)ymin, r3 = (int)ymax;
    if(!valid){ r0=0; r1=0; r2=0; r3=0; }
    #pragma unroll
    for(int d=0;d<7;++d) out[t*7+d] = bf[d];
    out[N*7 + t] = sf;
    out[N*8 + t] = valid ? 1.f : 0.f;
    out[N*9 + t*4 + 0] = (float)r0;
    out[N*9 + t*4 + 1] = (float)r1;
    out[N*9 + t*4 + 2] = (float)r2;
    out[N*9 + t*4 + 3] = (float)r3;
}

extern "C" void kernel_launch(void* const* d_in, const int* in_sizes, int n_in,
                              void* d_out, int out_size, void* d_ws, size_t ws_size,
                              hipStream_t stream) {
    const float* boxes  = (const float*)d_in[0];
    const float* scores = (const float*)d_in[1];
    const int*   fhp    = (const int*)d_in[2];
    const int*   fwp    = (const int*)d_in[3];
    float* out = (float*)d_out;
    ull* adj = (ull*)d_ws;               // 32768 bytes

    adj_kernel<<<N, 512, 0, stream>>>(boxes, adj);
    cluster_fuse_kernel<<<1, 512, 0, stream>>>(boxes, scores, adj, fhp, fwp, out);
}